// Round 9
// baseline (235.843 us; speedup 1.0000x reference)
//
#include <hip/hip_runtime.h>
#include <hip/hip_bf16.h>
#include <stdint.h>

// B=8, T=1024, C=1024, H=16, D=64. Inputs/outputs FLOAT32 (per reference);
// internal compute bf16 MFMA + fp32 accumulate (threshold is 2% relative).
// 4-kernel pipeline: prep -> gemm_qkv (+RoPE) -> flash -> gemm_out.
// R9: flash at QBLK=512 is LDS-read-bound (per-g ak/av re-reads: 512KB/kt/CU
// vs 2483 MFMA cyc). R6's g-invariant hoist was null ONLY because QBLK=128
// was supply-masked; re-apply it here: one ak per (ni,ks) and one av per
// (mi,ks) feed all 4 g's MFMAs -> 72 -> 24 b128 reads/wave/kt. Accumulation
// order per element unchanged. Everything else byte-identical to R8.

typedef __attribute__((ext_vector_type(8))) short short8;
typedef __attribute__((ext_vector_type(4))) float floatx4;
typedef __attribute__((ext_vector_type(2))) unsigned int uint2v;

#define DEV static __device__ __forceinline__

#if __has_builtin(__builtin_amdgcn_exp2f)
#define EXP2(x) __builtin_amdgcn_exp2f(x)
#else
#define EXP2(x) exp2f(x)
#endif

DEV uint16_t f2bf(float f) {
  union { float f; uint32_t i; } v; v.f = f;
  uint32_t u = v.i;
  return (uint16_t)((u + 0x7fffu + ((u >> 16) & 1u)) >> 16);  // RNE
}

// pack two floats -> two bf16 in one dword (v_cvt_pk_bf16_f32 on gfx950)
DEV uint32_t pkbf(float a, float b) {
  __hip_bfloat162 h = __float22bfloat162_rn(make_float2(a, b));
  union { __hip_bfloat162 h; uint32_t u; } v; v.h = h;
  return v.u;
}

// async 16B global->LDS; LDS dest = wave-uniform base + lane*16 (m104/m108)
DEV void async_load16(const uint16_t* g, uint16_t* l) {
  __builtin_amdgcn_global_load_lds(
      (const __attribute__((address_space(1))) void*)g,
      (__attribute__((address_space(3))) void*)l, 16, 0, 0);
}

// ---------------------------------------------------------------- prep (fused)
__global__ __launch_bounds__(256) void prep(
    const float* __restrict__ x, const float* __restrict__ W_attn,
    const float* __restrict__ W_proj, const float* __restrict__ omega,
    uint16_t* __restrict__ xb, uint16_t* __restrict__ Wt_attn,
    uint16_t* __restrict__ Wt_proj, float2* __restrict__ tab) {
  __shared__ uint16_t tile[64][65];
  const int blk = blockIdx.x, tid = threadIdx.x;
  if (blk < 4096) {
    const size_t base = ((size_t)blk * 256 + tid) * 8;
    floatx4 a = *(const floatx4*)(x + base);
    floatx4 b = *(const floatx4*)(x + base + 4);
    short8 s;
    s[0] = (short)f2bf(a[0]); s[1] = (short)f2bf(a[1]);
    s[2] = (short)f2bf(a[2]); s[3] = (short)f2bf(a[3]);
    s[4] = (short)f2bf(b[0]); s[5] = (short)f2bf(b[1]);
    s[6] = (short)f2bf(b[2]); s[7] = (short)f2bf(b[3]);
    *(short8*)(xb + base) = s;
  } else if (blk < 5120) {
    const float* in;
    uint16_t* out;
    int R = 1024, Ccols, bx, by;
    if (blk < 4864) {
      const int idx = blk - 4096;
      in = W_attn; out = Wt_attn; Ccols = 3072;
      bx = idx % 48; by = idx / 48;
    } else {
      const int idx = blk - 4864;
      in = W_proj; out = Wt_proj; Ccols = 1024;
      bx = idx % 16; by = idx / 16;
    }
    const int tx = tid & 63, ty = tid >> 6;
    const int c0 = bx * 64, r0 = by * 64;
    #pragma unroll
    for (int i = 0; i < 64; i += 4)
      tile[ty + i][tx] = f2bf(in[(size_t)(r0 + ty + i) * Ccols + c0 + tx]);
    __syncthreads();
    #pragma unroll
    for (int i = 0; i < 64; i += 4)
      out[(size_t)(c0 + ty + i) * R + r0 + tx] = tile[tx][ty + i];
  } else {
    const int idx = (blk - 5120) * 256 + tid;  // 0..32767
    const int t = idx >> 5, d = idx & 31;
    float s, c;
    sincosf((float)t * omega[d], &s, &c);
    tab[idx] = make_float2(c, s);
  }
}

// --------------------------------------------------------- 8-wave GEMM core
// 256x128, BK=64, 3-deep LDS pipeline, counted vmcnt(6). (R1 core, ~73us on
// gemm_qkv.) Buffer q=kt%3 holds K-tile kt; kt stages kt+2 into (kt+2)%3,
// last read at kt-1 (two barriers earlier) => race-free.
DEV void gemm_core8(const uint16_t* __restrict__ Ag,
                    const uint16_t* __restrict__ Bg,
                    int row0, int col0,
                    uint16_t* As, uint16_t* Bs, floatx4 (&acc)[4][4]) {
  const int tid = threadIdx.x;
  const int wave = tid >> 6, lane = tid & 63;
  const int l15 = lane & 15, quad = lane >> 4;
  const int wrow = wave >> 1, wcol = wave & 1;
  const int sw = l15 & 7;
  const int K = 1024;

  size_t aoff[4], boff[2];
  #pragma unroll
  for (int i = 0; i < 4; i++) {
    const int e = i * 512 + tid;
    const int r = e >> 3, c = e & 7, j = c ^ (r & 7);
    aoff[i] = (size_t)(row0 + r) * K + j * 8;
  }
  #pragma unroll
  for (int i = 0; i < 2; i++) {
    const int e = i * 512 + tid;
    const int r = e >> 3, c = e & 7, j = c ^ (r & 7);
    boff[i] = (size_t)(col0 + r) * K + j * 8;
  }

  #pragma unroll
  for (int t = 0; t < 2; t++) {
    #pragma unroll
    for (int i = 0; i < 2; i++)
      async_load16(Bg + boff[i] + (size_t)t * 64, Bs + t * 8192 + (i * 512 + tid) * 8);
    #pragma unroll
    for (int i = 0; i < 4; i++)
      async_load16(Ag + aoff[i] + (size_t)t * 64, As + t * 16384 + (i * 512 + tid) * 8);
  }

  const floatx4 z4 = {0.f, 0.f, 0.f, 0.f};
  #pragma unroll
  for (int mi = 0; mi < 4; mi++)
    #pragma unroll
    for (int ni = 0; ni < 4; ni++) acc[mi][ni] = z4;

  asm volatile("s_waitcnt vmcnt(6)" ::: "memory");
  __builtin_amdgcn_s_barrier();

  int qa = 0, q2 = 2;
  const int arow = wrow * 64 + l15;
  const int brow = wcol * 64 + l15;
  for (int kt = 0; kt < 16; ++kt) {
    const uint16_t* Aq = As + qa * 16384;
    const uint16_t* Bq = Bs + qa * 8192;
    uint16_t* As2 = As + q2 * 16384;
    uint16_t* Bs2 = Bs + q2 * 8192;
    const size_t k2 = (size_t)(kt + 2) * 64;

    // ---------------- phase 1 (ks = 0)
    short8 af[4], bfr[4];
    #pragma unroll
    for (int mi = 0; mi < 4; mi++)
      af[mi] = *(const short8*)(Aq + (arow + mi * 16) * 64 + ((quad ^ sw) * 8));
    #pragma unroll
    for (int ni = 0; ni < 4; ni++)
      bfr[ni] = *(const short8*)(Bq + (brow + ni * 16) * 64 + ((quad ^ sw) * 8));
    if (kt < 14) {
      #pragma unroll
      for (int i = 0; i < 2; i++)
        async_load16(Bg + boff[i] + k2, Bs2 + (i * 512 + tid) * 8);
      #pragma unroll
      for (int i = 0; i < 2; i++)
        async_load16(Ag + aoff[i] + k2, As2 + (i * 512 + tid) * 8);
    }
    __builtin_amdgcn_s_barrier();
    asm volatile("s_waitcnt lgkmcnt(0)" ::: "memory");
    __builtin_amdgcn_s_setprio(1);
    #pragma unroll
    for (int mi = 0; mi < 4; mi++)
      #pragma unroll
      for (int ni = 0; ni < 4; ni++)
        acc[mi][ni] = __builtin_amdgcn_mfma_f32_16x16x32_bf16(
            af[mi], bfr[ni], acc[mi][ni], 0, 0, 0);
    __builtin_amdgcn_s_setprio(0);
    __builtin_amdgcn_s_barrier();

    // ---------------- phase 2 (ks = 1)
    #pragma unroll
    for (int mi = 0; mi < 4; mi++)
      af[mi] = *(const short8*)(Aq + (arow + mi * 16) * 64 + (((4 + quad) ^ sw) * 8));
    #pragma unroll
    for (int ni = 0; ni < 4; ni++)
      bfr[ni] = *(const short8*)(Bq + (brow + ni * 16) * 64 + (((4 + quad) ^ sw) * 8));
    if (kt < 14) {
      #pragma unroll
      for (int i = 2; i < 4; i++)
        async_load16(Ag + aoff[i] + k2, As2 + (i * 512 + tid) * 8);
      asm volatile("s_waitcnt vmcnt(6)" ::: "memory");
    } else if (kt == 14) {
      asm volatile("s_waitcnt vmcnt(0)" ::: "memory");
    }
    __builtin_amdgcn_s_barrier();
    asm volatile("s_waitcnt lgkmcnt(0)" ::: "memory");
    __builtin_amdgcn_s_setprio(1);
    #pragma unroll
    for (int mi = 0; mi < 4; mi++)
      #pragma unroll
      for (int ni = 0; ni < 4; ni++)
        acc[mi][ni] = __builtin_amdgcn_mfma_f32_16x16x32_bf16(
            af[mi], bfr[ni], acc[mi][ni], 0, 0, 0);
    __builtin_amdgcn_s_setprio(0);
    __builtin_amdgcn_s_barrier();

    qa = (qa == 2) ? 0 : qa + 1;
    q2 = (q2 == 2) ? 0 : q2 + 1;
  }
}

// ---------------------------------------------------------------- GEMM1 + RoPE
// qkv = xb @ Wt_attn^T, fused RoPE + head relayout (R1 version).
__global__ __launch_bounds__(512) void gemm_qkv(
    const uint16_t* __restrict__ A, const uint16_t* __restrict__ Bt,
    const float2* __restrict__ tab,
    uint16_t* __restrict__ Qr, uint16_t* __restrict__ Kr, uint16_t* __restrict__ Vt) {
  __shared__ __align__(16) uint16_t As[3 * 256 * 64];   // 96 KB
  __shared__ __align__(16) uint16_t Bs[3 * 128 * 64];   // 48 KB
  const int row0 = blockIdx.y * 256, col0 = blockIdx.x * 128;
  floatx4 acc[4][4];
  gemm_core8(A, Bt, row0, col0, As, Bs, acc);

  const int tid = threadIdx.x;
  const int wave = tid >> 6, lane = tid & 63;
  const int l15 = lane & 15, quad = lane >> 4;
  const int cblk = col0 + (wave & 1) * 64;
  const int region = cblk >> 10;       // 0:q 1:k 2:v
  const int h = (cblk & 1023) >> 6;
  const int rr = row0 + (wave >> 1) * 64;
  const int b = rr >> 10;
  const int tbase = rr & 1023;
  const size_t bh = (size_t)b * 16 + h;

  if (region < 2) {
    uint16_t* dst = (region == 0) ? Qr : Kr;
    // q scale: 1/sqrt(64) * log2(e) -> softmax becomes 2^s (raw v_exp_f32)
    const float scl = (region == 0) ? 0.125f * 1.44269504088896f : 1.0f;
    #pragma unroll
    for (int mi = 0; mi < 4; mi++)
      #pragma unroll
      for (int r = 0; r < 4; r++) {
        const int t = tbase + mi * 16 + quad * 4 + r;
        const size_t base = (bh * 1024 + t) * 64;
        const float2 cs0 = tab[t * 32 + l15];
        const float2 cs1 = tab[t * 32 + l15 + 16];
        {  // pair d=l15 (acc ni=0) with d+32 (ni=2)
          float x1 = acc[mi][0][r], x2 = acc[mi][2][r];
          dst[base + l15]      = f2bf((x1 * cs0.x - x2 * cs0.y) * scl);
          dst[base + l15 + 32] = f2bf((x2 * cs0.x + x1 * cs0.y) * scl);
        }
        {  // pair d=16+l15 (ni=1) with d+32 (ni=3)
          float x1 = acc[mi][1][r], x2 = acc[mi][3][r];
          dst[base + 16 + l15]      = f2bf((x1 * cs1.x - x2 * cs1.y) * scl);
          dst[base + 16 + l15 + 32] = f2bf((x2 * cs1.x + x1 * cs1.y) * scl);
        }
      }
  } else {
    // V transposed: Vt[bh*64*1024 + d*1024 + t]
    #pragma unroll
    for (int mi = 0; mi < 4; mi++)
      #pragma unroll
      for (int ni = 0; ni < 4; ni++) {
        const int d = ni * 16 + l15;
        #pragma unroll
        for (int r = 0; r < 4; r++) {
          const int t = tbase + mi * 16 + quad * 4 + r;
          Vt[bh * 65536 + (size_t)d * 1024 + t] = f2bf(acc[mi][ni][r]);
        }
      }
  }
}

// ---------------------------------------------------------------- GEMM2 (fp32 out)
// out(8192x1024 fp32) = Y bf16 @ Wt_proj^T. 256 blocks, XCD-swizzled.
__global__ __launch_bounds__(512) void gemm_out(
    const uint16_t* __restrict__ A, const uint16_t* __restrict__ Bt,
    float* __restrict__ Cmat, int M, int N, int K) {
  __shared__ __align__(16) uint16_t As[3 * 256 * 64];
  __shared__ __align__(16) uint16_t Bs[3 * 128 * 64];
  const int bid = blockIdx.x;
  const int xcd = bid & 7, slot = bid >> 3;        // slot 0..31
  const int row0 = (xcd * 4 + (slot & 3)) * 256;   // 0..31 * 256
  const int col0 = (slot >> 2) * 128;              // 0..7 * 128
  floatx4 acc[4][4];
  gemm_core8(A, Bt, row0, col0, As, Bs, acc);

  const int tid = threadIdx.x;
  const int wave = tid >> 6, lane = tid & 63;
  const int l15 = lane & 15, quad = lane >> 4;
  #pragma unroll
  for (int mi = 0; mi < 4; mi++)
    #pragma unroll
    for (int ni = 0; ni < 4; ni++) {
      const int col = col0 + (wave & 1) * 64 + ni * 16 + l15;
      #pragma unroll
      for (int r = 0; r < 4; r++) {
        const int row = row0 + (wave >> 1) * 64 + mi * 16 + quad * 4 + r;
        Cmat[(size_t)row * N + col] = acc[mi][ni][r];
      }
    }
}

// ---------------------------------------------------------------- flash attention
// R8 geometry (QBLK=512, 8 waves, grid 256 = 1 block/CU; dbuf + vmcnt(2))
// with R6's g-invariant read hoist: one ak read per (ni,ks) and one av read
// per (mi,ks) feed all 4 g's MFMAs. 72 -> 24 b128 reads/wave/kt. Per-element
// accumulation order (ks=0 then ks=1) unchanged vs R8; Ps write->read stays
// same-wave in-order (all g-writes precede all bp reads within the wave).
#define FLD 72  // P LDS stride (padded, b64 writes are 2-way = free)

__global__ __launch_bounds__(512) void flash_attn(
    const uint16_t* __restrict__ Qr, const uint16_t* __restrict__ Kr,
    const uint16_t* __restrict__ Vt, uint16_t* __restrict__ Y) {
  __shared__ __align__(16) uint16_t Ks[2][64 * 64];
  __shared__ __align__(16) uint16_t Vs[2][64 * 64];
  __shared__ __align__(16) uint16_t Ps[512 * FLD];
  const int tid = threadIdx.x;
  const int wv = tid >> 6, lane = tid & 63;
  const int l15 = lane & 15, quad = lane >> 4;
  const int sw = l15 & 7;
  const int bh = blockIdx.x & 127, qt = blockIdx.x >> 7;   // qt in 0..1
  const int b = bh >> 4, h = bh & 15;
  const int q0 = qt * 512;
  const uint16_t* Qbh = Qr + (size_t)bh * 65536;
  const uint16_t* Kbh = Kr + (size_t)bh * 65536;
  const uint16_t* Vbh = Vt + (size_t)bh * 65536;

  // Q frags (B-operand), 4 groups of 16 q-rows per wave; loop-invariant.
  short8 bq[4][2];
  #pragma unroll
  for (int g = 0; g < 4; g++)
    #pragma unroll
    for (int ks = 0; ks < 2; ks++)
      bq[g][ks] = *(const short8*)(Qbh +
          (size_t)(q0 + wv * 64 + g * 16 + l15) * 64 + ks * 32 + quad * 8);

  float psum[4] = {0.f, 0.f, 0.f, 0.f};
  const floatx4 z4 = {0.f, 0.f, 0.f, 0.f};
  floatx4 oacc[4][4];
  #pragma unroll
  for (int g = 0; g < 4; g++)
    #pragma unroll
    for (int mi = 0; mi < 4; mi++) oacc[g][mi] = z4;

  // stage tile kt into buffer: 512 threads, 1 K-chunk + 1 V-chunk each
  #define STAGE_KV(kt_, Kd_, Vd_)                                               \
    {                                                                           \
      const int e = tid;                                                        \
      const int r = e >> 3;                                                     \
      const int j = (e & 7) ^ (r & 7);                                          \
      async_load16(Kbh + (size_t)((kt_) * 64 + r) * 64 + j * 8, (Kd_) + e * 8); \
      async_load16(Vbh + (size_t)r * 1024 + (kt_) * 64 + j * 8, (Vd_) + e * 8); \
    }

  STAGE_KV(0, Ks[0], Vs[0]);
  STAGE_KV(1, Ks[1], Vs[1]);
  asm volatile("s_waitcnt vmcnt(2)" ::: "memory");  // tile 0 landed (own wave)
  __builtin_amdgcn_s_barrier();                     // ...and for all waves

  for (int kt = 0; kt < 16; kt++) {
    const int buf = kt & 1;

    // ---- S^T = K·Q^T for all 4 g; single ak read per (ni,ks)
    floatx4 sacc[4][4];
    #pragma unroll
    for (int g = 0; g < 4; g++)
      #pragma unroll
      for (int ni = 0; ni < 4; ni++) sacc[g][ni] = z4;
    __builtin_amdgcn_s_setprio(1);
    #pragma unroll
    for (int ni = 0; ni < 4; ni++) {
      #pragma unroll
      for (int ks = 0; ks < 2; ks++) {
        short8 ak = *(const short8*)(&Ks[buf][(ni * 16 + l15) * 64 +
                                             (((ks * 4 + quad) ^ sw) * 8)]);
        #pragma unroll
        for (int g = 0; g < 4; g++)
          sacc[g][ni] = __builtin_amdgcn_mfma_f32_16x16x32_bf16(
              ak, bq[g][ks], sacc[g][ni], 0, 0, 0);
      }
    }
    __builtin_amdgcn_s_setprio(0);

    // ---- p = 2^s; per-lane row-sum; packed bf16 P^T -> Ps[q][key]
    #pragma unroll
    for (int g = 0; g < 4; g++) {
      const int qrow = wv * 64 + g * 16 + l15;
      #pragma unroll
      for (int ni = 0; ni < 4; ni++) {
        float p0 = EXP2(sacc[g][ni][0]), p1 = EXP2(sacc[g][ni][1]);
        float p2 = EXP2(sacc[g][ni][2]), p3 = EXP2(sacc[g][ni][3]);
        psum[g] += (p0 + p1) + (p2 + p3);
        uint2v pk; pk[0] = pkbf(p0, p1); pk[1] = pkbf(p2, p3);
        *(uint2v*)(&Ps[qrow * FLD + ni * 16 + quad * 4]) = pk;
      }
    }

    // ---- O^T += V^T·P for all 4 g; single av read per (mi,ks)
    short8 bp[4][2];
    #pragma unroll
    for (int g = 0; g < 4; g++) {
      const int qrow = wv * 64 + g * 16 + l15;
      #pragma unroll
      for (int ks = 0; ks < 2; ks++)
        bp[g][ks] = *(const short8*)(&Ps[qrow * FLD + ks * 32 + quad * 8]);
    }
    __builtin_amdgcn_s_setprio(1);
    #pragma unroll
    for (int mi = 0; mi < 4; mi++) {
      #pragma unroll
      for (int ks = 0; ks < 2; ks++) {
        short8 av = *(const short8*)(&Vs[buf][(mi * 16 + l15) * 64 +
                                             (((ks * 4 + quad) ^ sw) * 8)]);
        #pragma unroll
        for (int g = 0; g < 4; g++)
          oacc[g][mi] = __builtin_amdgcn_mfma_f32_16x16x32_bf16(
              av, bp[g][ks], oacc[g][mi], 0, 0, 0);
      }
    }
    __builtin_amdgcn_s_setprio(0);

    // ---- pipeline: all waves done reading buf -> refill it with kt+2
    __builtin_amdgcn_s_barrier();
    if (kt + 2 < 16) { STAGE_KV(kt + 2, Ks[buf], Vs[buf]); }
    if (kt + 1 < 16) {
      if (kt + 2 < 16) asm volatile("s_waitcnt vmcnt(2)" ::: "memory");
      else             asm volatile("s_waitcnt vmcnt(0)" ::: "memory");
      __builtin_amdgcn_s_barrier();   // tile kt+1 landed for all waves
    }
  }
  #undef STAGE_KV

  #pragma unroll
  for (int g = 0; g < 4; g++) {
    float l_tot = psum[g];
    l_tot += __shfl_xor(l_tot, 16, 64);
    l_tot += __shfl_xor(l_tot, 32, 64);
    const float linv = 1.0f / l_tot;
    const int t = q0 + wv * 64 + g * 16 + l15;
    #pragma unroll
    for (int mi = 0; mi < 4; mi++) {
      uint2v yk;
      yk[0] = pkbf(oacc[g][mi][0] * linv, oacc[g][mi][1] * linv);
      yk[1] = pkbf(oacc[g][mi][2] * linv, oacc[g][mi][3] * linv);
      *(uint2v*)(Y + (size_t)(b * 1024 + t) * 1024 + h * 64 + mi * 16 + quad * 4) = yk;
    }
  }
}

// ---------------------------------------------------------------- launch
extern "C" void kernel_launch(void* const* d_in, const int* in_sizes, int n_in,
                              void* d_out, int out_size, void* d_ws, size_t ws_size,
                              hipStream_t stream) {
  const float* x      = (const float*)d_in[0];  // [8,1024,1024] fp32
  const float* W_attn = (const float*)d_in[1];  // [1024,3072]   fp32
  const float* W_proj = (const float*)d_in[2];  // [1024,1024]   fp32
  const float* omega  = (const float*)d_in[3];  // [32]          fp32
  float* out = (float*)d_out;                   // [8192,1024]   fp32

  uint16_t* wsp     = (uint16_t*)d_ws;
  uint16_t* xb      = wsp;                                  // 8,388,608
  uint16_t* Wt_attn = xb + (size_t)8192 * 1024;             // 3,145,728
  uint16_t* Wt_proj = Wt_attn + (size_t)3072 * 1024;        // 1,048,576
  uint16_t* Qr      = Wt_proj + (size_t)1024 * 1024;        // 8,388,608
  uint16_t* Kr      = Qr + (size_t)128 * 1024 * 64;         // 8,388,608
  uint16_t* Vt      = Kr + (size_t)128 * 1024 * 64;         // 8,388,608
  float2*   ropet   = (float2*)(Vt + (size_t)128 * 1024 * 64);  // 32768 float2
  uint16_t* Y       = xb;   // xb dead after gemm_qkv

  prep<<<5248, 256, 0, stream>>>(x, W_attn, W_proj, omega, xb, Wt_attn, Wt_proj, ropet);
  gemm_qkv<<<dim3(24, 32), 512, 0, stream>>>(xb, Wt_attn, ropet, Qr, Kr, Vt);
  flash_attn<<<256, 512, 0, stream>>>(Qr, Kr, Vt, Y);
  gemm_out<<<256, 512, 0, stream>>>(Y, Wt_proj, out, 8192, 1024, 1024);
}

// Round 10
// 232.803 us; speedup vs baseline: 1.0131x; 1.0131x over previous
//
#include <hip/hip_runtime.h>
#include <hip/hip_bf16.h>
#include <stdint.h>

// B=8, T=1024, C=1024, H=16, D=64. Inputs/outputs FLOAT32 (per reference);
// internal compute bf16 MFMA + fp32 accumulate (threshold is 2% relative).
// 4-kernel pipeline: prep -> gemm_qkv (+RoPE) -> flash -> gemm_out.
// R10: revert flash to R8 exact (R9 hoist null + VGPR pressure; flash responds
// only to traffic cuts). Add T1 XCD swizzle to gemm_qkv (was only on gemm_out):
// bid&7 = xcd owns 4 contiguous row-panels x 24 col-blocks -> A-panels become
// XCD-local-L2-resident instead of replicated 8x. Bijective (768%8==0).

typedef __attribute__((ext_vector_type(8))) short short8;
typedef __attribute__((ext_vector_type(4))) float floatx4;
typedef __attribute__((ext_vector_type(2))) unsigned int uint2v;

#define DEV static __device__ __forceinline__

#if __has_builtin(__builtin_amdgcn_exp2f)
#define EXP2(x) __builtin_amdgcn_exp2f(x)
#else
#define EXP2(x) exp2f(x)
#endif

DEV uint16_t f2bf(float f) {
  union { float f; uint32_t i; } v; v.f = f;
  uint32_t u = v.i;
  return (uint16_t)((u + 0x7fffu + ((u >> 16) & 1u)) >> 16);  // RNE
}

// pack two floats -> two bf16 in one dword (v_cvt_pk_bf16_f32 on gfx950)
DEV uint32_t pkbf(float a, float b) {
  __hip_bfloat162 h = __float22bfloat162_rn(make_float2(a, b));
  union { __hip_bfloat162 h; uint32_t u; } v; v.h = h;
  return v.u;
}

// async 16B global->LDS; LDS dest = wave-uniform base + lane*16 (m104/m108)
DEV void async_load16(const uint16_t* g, uint16_t* l) {
  __builtin_amdgcn_global_load_lds(
      (const __attribute__((address_space(1))) void*)g,
      (__attribute__((address_space(3))) void*)l, 16, 0, 0);
}

// ---------------------------------------------------------------- prep (fused)
__global__ __launch_bounds__(256) void prep(
    const float* __restrict__ x, const float* __restrict__ W_attn,
    const float* __restrict__ W_proj, const float* __restrict__ omega,
    uint16_t* __restrict__ xb, uint16_t* __restrict__ Wt_attn,
    uint16_t* __restrict__ Wt_proj, float2* __restrict__ tab) {
  __shared__ uint16_t tile[64][65];
  const int blk = blockIdx.x, tid = threadIdx.x;
  if (blk < 4096) {
    const size_t base = ((size_t)blk * 256 + tid) * 8;
    floatx4 a = *(const floatx4*)(x + base);
    floatx4 b = *(const floatx4*)(x + base + 4);
    short8 s;
    s[0] = (short)f2bf(a[0]); s[1] = (short)f2bf(a[1]);
    s[2] = (short)f2bf(a[2]); s[3] = (short)f2bf(a[3]);
    s[4] = (short)f2bf(b[0]); s[5] = (short)f2bf(b[1]);
    s[6] = (short)f2bf(b[2]); s[7] = (short)f2bf(b[3]);
    *(short8*)(xb + base) = s;
  } else if (blk < 5120) {
    const float* in;
    uint16_t* out;
    int R = 1024, Ccols, bx, by;
    if (blk < 4864) {
      const int idx = blk - 4096;
      in = W_attn; out = Wt_attn; Ccols = 3072;
      bx = idx % 48; by = idx / 48;
    } else {
      const int idx = blk - 4864;
      in = W_proj; out = Wt_proj; Ccols = 1024;
      bx = idx % 16; by = idx / 16;
    }
    const int tx = tid & 63, ty = tid >> 6;
    const int c0 = bx * 64, r0 = by * 64;
    #pragma unroll
    for (int i = 0; i < 64; i += 4)
      tile[ty + i][tx] = f2bf(in[(size_t)(r0 + ty + i) * Ccols + c0 + tx]);
    __syncthreads();
    #pragma unroll
    for (int i = 0; i < 64; i += 4)
      out[(size_t)(c0 + ty + i) * R + r0 + tx] = tile[tx][ty + i];
  } else {
    const int idx = (blk - 5120) * 256 + tid;  // 0..32767
    const int t = idx >> 5, d = idx & 31;
    float s, c;
    sincosf((float)t * omega[d], &s, &c);
    tab[idx] = make_float2(c, s);
  }
}

// --------------------------------------------------------- 8-wave GEMM core
// 256x128, BK=64, 3-deep LDS pipeline, counted vmcnt(6). (R1 core.)
// Buffer q=kt%3 holds K-tile kt; kt stages kt+2 into (kt+2)%3, last read at
// kt-1 (two barriers earlier) => race-free.
DEV void gemm_core8(const uint16_t* __restrict__ Ag,
                    const uint16_t* __restrict__ Bg,
                    int row0, int col0,
                    uint16_t* As, uint16_t* Bs, floatx4 (&acc)[4][4]) {
  const int tid = threadIdx.x;
  const int wave = tid >> 6, lane = tid & 63;
  const int l15 = lane & 15, quad = lane >> 4;
  const int wrow = wave >> 1, wcol = wave & 1;
  const int sw = l15 & 7;
  const int K = 1024;

  size_t aoff[4], boff[2];
  #pragma unroll
  for (int i = 0; i < 4; i++) {
    const int e = i * 512 + tid;
    const int r = e >> 3, c = e & 7, j = c ^ (r & 7);
    aoff[i] = (size_t)(row0 + r) * K + j * 8;
  }
  #pragma unroll
  for (int i = 0; i < 2; i++) {
    const int e = i * 512 + tid;
    const int r = e >> 3, c = e & 7, j = c ^ (r & 7);
    boff[i] = (size_t)(col0 + r) * K + j * 8;
  }

  #pragma unroll
  for (int t = 0; t < 2; t++) {
    #pragma unroll
    for (int i = 0; i < 2; i++)
      async_load16(Bg + boff[i] + (size_t)t * 64, Bs + t * 8192 + (i * 512 + tid) * 8);
    #pragma unroll
    for (int i = 0; i < 4; i++)
      async_load16(Ag + aoff[i] + (size_t)t * 64, As + t * 16384 + (i * 512 + tid) * 8);
  }

  const floatx4 z4 = {0.f, 0.f, 0.f, 0.f};
  #pragma unroll
  for (int mi = 0; mi < 4; mi++)
    #pragma unroll
    for (int ni = 0; ni < 4; ni++) acc[mi][ni] = z4;

  asm volatile("s_waitcnt vmcnt(6)" ::: "memory");
  __builtin_amdgcn_s_barrier();

  int qa = 0, q2 = 2;
  const int arow = wrow * 64 + l15;
  const int brow = wcol * 64 + l15;
  for (int kt = 0; kt < 16; ++kt) {
    const uint16_t* Aq = As + qa * 16384;
    const uint16_t* Bq = Bs + qa * 8192;
    uint16_t* As2 = As + q2 * 16384;
    uint16_t* Bs2 = Bs + q2 * 8192;
    const size_t k2 = (size_t)(kt + 2) * 64;

    // ---------------- phase 1 (ks = 0)
    short8 af[4], bfr[4];
    #pragma unroll
    for (int mi = 0; mi < 4; mi++)
      af[mi] = *(const short8*)(Aq + (arow + mi * 16) * 64 + ((quad ^ sw) * 8));
    #pragma unroll
    for (int ni = 0; ni < 4; ni++)
      bfr[ni] = *(const short8*)(Bq + (brow + ni * 16) * 64 + ((quad ^ sw) * 8));
    if (kt < 14) {
      #pragma unroll
      for (int i = 0; i < 2; i++)
        async_load16(Bg + boff[i] + k2, Bs2 + (i * 512 + tid) * 8);
      #pragma unroll
      for (int i = 0; i < 2; i++)
        async_load16(Ag + aoff[i] + k2, As2 + (i * 512 + tid) * 8);
    }
    __builtin_amdgcn_s_barrier();
    asm volatile("s_waitcnt lgkmcnt(0)" ::: "memory");
    __builtin_amdgcn_s_setprio(1);
    #pragma unroll
    for (int mi = 0; mi < 4; mi++)
      #pragma unroll
      for (int ni = 0; ni < 4; ni++)
        acc[mi][ni] = __builtin_amdgcn_mfma_f32_16x16x32_bf16(
            af[mi], bfr[ni], acc[mi][ni], 0, 0, 0);
    __builtin_amdgcn_s_setprio(0);
    __builtin_amdgcn_s_barrier();

    // ---------------- phase 2 (ks = 1)
    #pragma unroll
    for (int mi = 0; mi < 4; mi++)
      af[mi] = *(const short8*)(Aq + (arow + mi * 16) * 64 + (((4 + quad) ^ sw) * 8));
    #pragma unroll
    for (int ni = 0; ni < 4; ni++)
      bfr[ni] = *(const short8*)(Bq + (brow + ni * 16) * 64 + (((4 + quad) ^ sw) * 8));
    if (kt < 14) {
      #pragma unroll
      for (int i = 2; i < 4; i++)
        async_load16(Ag + aoff[i] + k2, As2 + (i * 512 + tid) * 8);
      asm volatile("s_waitcnt vmcnt(6)" ::: "memory");
    } else if (kt == 14) {
      asm volatile("s_waitcnt vmcnt(0)" ::: "memory");
    }
    __builtin_amdgcn_s_barrier();
    asm volatile("s_waitcnt lgkmcnt(0)" ::: "memory");
    __builtin_amdgcn_s_setprio(1);
    #pragma unroll
    for (int mi = 0; mi < 4; mi++)
      #pragma unroll
      for (int ni = 0; ni < 4; ni++)
        acc[mi][ni] = __builtin_amdgcn_mfma_f32_16x16x32_bf16(
            af[mi], bfr[ni], acc[mi][ni], 0, 0, 0);
    __builtin_amdgcn_s_setprio(0);
    __builtin_amdgcn_s_barrier();

    qa = (qa == 2) ? 0 : qa + 1;
    q2 = (q2 == 2) ? 0 : q2 + 1;
  }
}

// ---------------------------------------------------------------- GEMM1 + RoPE
// qkv = xb @ Wt_attn^T, fused RoPE + head relayout. R10: XCD-swizzled grid
// (768 blocks): xcd = bid&7 owns 4 contiguous row-panels x all 24 col-blocks
// (rows inner) -> A row-panels (4x0.5MB) stay resident in that XCD's L2.
__global__ __launch_bounds__(512) void gemm_qkv(
    const uint16_t* __restrict__ A, const uint16_t* __restrict__ Bt,
    const float2* __restrict__ tab,
    uint16_t* __restrict__ Qr, uint16_t* __restrict__ Kr, uint16_t* __restrict__ Vt) {
  __shared__ __align__(16) uint16_t As[3 * 256 * 64];   // 96 KB
  __shared__ __align__(16) uint16_t Bs[3 * 128 * 64];   // 48 KB
  const int bid = blockIdx.x;
  const int xcd = bid & 7, slot = bid >> 3;        // slot 0..95
  const int row0 = (xcd * 4 + (slot & 3)) * 256;   // 0..31 * 256
  const int col0 = (slot >> 2) * 128;              // 0..23 * 128
  floatx4 acc[4][4];
  gemm_core8(A, Bt, row0, col0, As, Bs, acc);

  const int tid = threadIdx.x;
  const int wave = tid >> 6, lane = tid & 63;
  const int l15 = lane & 15, quad = lane >> 4;
  const int cblk = col0 + (wave & 1) * 64;
  const int region = cblk >> 10;       // 0:q 1:k 2:v
  const int h = (cblk & 1023) >> 6;
  const int rr = row0 + (wave >> 1) * 64;
  const int b = rr >> 10;
  const int tbase = rr & 1023;
  const size_t bh = (size_t)b * 16 + h;

  if (region < 2) {
    uint16_t* dst = (region == 0) ? Qr : Kr;
    // q scale: 1/sqrt(64) * log2(e) -> softmax becomes 2^s (raw v_exp_f32)
    const float scl = (region == 0) ? 0.125f * 1.44269504088896f : 1.0f;
    #pragma unroll
    for (int mi = 0; mi < 4; mi++)
      #pragma unroll
      for (int r = 0; r < 4; r++) {
        const int t = tbase + mi * 16 + quad * 4 + r;
        const size_t base = (bh * 1024 + t) * 64;
        const float2 cs0 = tab[t * 32 + l15];
        const float2 cs1 = tab[t * 32 + l15 + 16];
        {  // pair d=l15 (acc ni=0) with d+32 (ni=2)
          float x1 = acc[mi][0][r], x2 = acc[mi][2][r];
          dst[base + l15]      = f2bf((x1 * cs0.x - x2 * cs0.y) * scl);
          dst[base + l15 + 32] = f2bf((x2 * cs0.x + x1 * cs0.y) * scl);
        }
        {  // pair d=16+l15 (ni=1) with d+32 (ni=3)
          float x1 = acc[mi][1][r], x2 = acc[mi][3][r];
          dst[base + 16 + l15]      = f2bf((x1 * cs1.x - x2 * cs1.y) * scl);
          dst[base + 16 + l15 + 32] = f2bf((x2 * cs1.x + x1 * cs1.y) * scl);
        }
      }
  } else {
    // V transposed: Vt[bh*64*1024 + d*1024 + t]
    #pragma unroll
    for (int mi = 0; mi < 4; mi++)
      #pragma unroll
      for (int ni = 0; ni < 4; ni++) {
        const int d = ni * 16 + l15;
        #pragma unroll
        for (int r = 0; r < 4; r++) {
          const int t = tbase + mi * 16 + quad * 4 + r;
          Vt[bh * 65536 + (size_t)d * 1024 + t] = f2bf(acc[mi][ni][r]);
        }
      }
  }
}

// ---------------------------------------------------------------- GEMM2 (fp32 out)
// out(8192x1024 fp32) = Y bf16 @ Wt_proj^T. 256 blocks, XCD-swizzled.
__global__ __launch_bounds__(512) void gemm_out(
    const uint16_t* __restrict__ A, const uint16_t* __restrict__ Bt,
    float* __restrict__ Cmat, int M, int N, int K) {
  __shared__ __align__(16) uint16_t As[3 * 256 * 64];
  __shared__ __align__(16) uint16_t Bs[3 * 128 * 64];
  const int bid = blockIdx.x;
  const int xcd = bid & 7, slot = bid >> 3;        // slot 0..31
  const int row0 = (xcd * 4 + (slot & 3)) * 256;   // 0..31 * 256
  const int col0 = (slot >> 2) * 128;              // 0..7 * 128
  floatx4 acc[4][4];
  gemm_core8(A, Bt, row0, col0, As, Bs, acc);

  const int tid = threadIdx.x;
  const int wave = tid >> 6, lane = tid & 63;
  const int l15 = lane & 15, quad = lane >> 4;
  #pragma unroll
  for (int mi = 0; mi < 4; mi++)
    #pragma unroll
    for (int ni = 0; ni < 4; ni++) {
      const int col = col0 + (wave & 1) * 64 + ni * 16 + l15;
      #pragma unroll
      for (int r = 0; r < 4; r++) {
        const int row = row0 + (wave >> 1) * 64 + mi * 16 + quad * 4 + r;
        Cmat[(size_t)row * N + col] = acc[mi][ni][r];
      }
    }
}

// ---------------------------------------------------------------- flash attention
// R8 exact (best measured): QBLK=512, 8 waves, grid 256 = 1 block/CU; per-wave
// 64 q-rows (g=0..3); 16x16 MFMA S^T formulation, no max-sub; Q pre-scaled
// 0.125*log2e -> p = 2^s. K/V dbuf, counted vmcnt(2); tail kt=14 -> vmcnt(0).
#define FLD 72  // P LDS stride (padded, b64 writes are 2-way = free)

__global__ __launch_bounds__(512) void flash_attn(
    const uint16_t* __restrict__ Qr, const uint16_t* __restrict__ Kr,
    const uint16_t* __restrict__ Vt, uint16_t* __restrict__ Y) {
  __shared__ __align__(16) uint16_t Ks[2][64 * 64];
  __shared__ __align__(16) uint16_t Vs[2][64 * 64];
  __shared__ __align__(16) uint16_t Ps[512 * FLD];
  const int tid = threadIdx.x;
  const int wv = tid >> 6, lane = tid & 63;
  const int l15 = lane & 15, quad = lane >> 4;
  const int sw = l15 & 7;
  const int bh = blockIdx.x & 127, qt = blockIdx.x >> 7;   // qt in 0..1
  const int b = bh >> 4, h = bh & 15;
  const int q0 = qt * 512;
  const uint16_t* Qbh = Qr + (size_t)bh * 65536;
  const uint16_t* Kbh = Kr + (size_t)bh * 65536;
  const uint16_t* Vbh = Vt + (size_t)bh * 65536;

  // Q frags (B-operand), 4 groups of 16 q-rows per wave; loop-invariant.
  short8 bq[4][2];
  #pragma unroll
  for (int g = 0; g < 4; g++)
    #pragma unroll
    for (int ks = 0; ks < 2; ks++)
      bq[g][ks] = *(const short8*)(Qbh +
          (size_t)(q0 + wv * 64 + g * 16 + l15) * 64 + ks * 32 + quad * 8);

  float psum[4] = {0.f, 0.f, 0.f, 0.f};
  const floatx4 z4 = {0.f, 0.f, 0.f, 0.f};
  floatx4 oacc[4][4];
  #pragma unroll
  for (int g = 0; g < 4; g++)
    #pragma unroll
    for (int mi = 0; mi < 4; mi++) oacc[g][mi] = z4;

  // stage tile kt into buffer: 512 threads, 1 K-chunk + 1 V-chunk each
  #define STAGE_KV(kt_, Kd_, Vd_)                                               \
    {                                                                           \
      const int e = tid;                                                        \
      const int r = e >> 3;                                                     \
      const int j = (e & 7) ^ (r & 7);                                          \
      async_load16(Kbh + (size_t)((kt_) * 64 + r) * 64 + j * 8, (Kd_) + e * 8); \
      async_load16(Vbh + (size_t)r * 1024 + (kt_) * 64 + j * 8, (Vd_) + e * 8); \
    }

  STAGE_KV(0, Ks[0], Vs[0]);
  STAGE_KV(1, Ks[1], Vs[1]);
  asm volatile("s_waitcnt vmcnt(2)" ::: "memory");  // tile 0 landed (own wave)
  __builtin_amdgcn_s_barrier();                     // ...and for all waves

  for (int kt = 0; kt < 16; kt++) {
    const int buf = kt & 1;
    #pragma unroll
    for (int g = 0; g < 4; g++) {
      const int qrow = wv * 64 + g * 16 + l15;
      // S^T = K·Q^T: rows = keys ni*16+quad*4+r, col = q-slice
      floatx4 sacc[4];
      __builtin_amdgcn_s_setprio(1);
      #pragma unroll
      for (int ni = 0; ni < 4; ni++) {
        sacc[ni] = z4;
        #pragma unroll
        for (int ks = 0; ks < 2; ks++) {
          short8 ak = *(const short8*)(&Ks[buf][(ni * 16 + l15) * 64 +
                                               (((ks * 4 + quad) ^ sw) * 8)]);
          sacc[ni] = __builtin_amdgcn_mfma_f32_16x16x32_bf16(ak, bq[g][ks], sacc[ni], 0, 0, 0);
        }
      }
      __builtin_amdgcn_s_setprio(0);
      // p = 2^s; per-lane row-sum; packed bf16 P^T -> Ps[q][key] (8B stores)
      #pragma unroll
      for (int ni = 0; ni < 4; ni++) {
        float p0 = EXP2(sacc[ni][0]), p1 = EXP2(sacc[ni][1]);
        float p2 = EXP2(sacc[ni][2]), p3 = EXP2(sacc[ni][3]);
        psum[g] += (p0 + p1) + (p2 + p3);
        uint2v pk; pk[0] = pkbf(p0, p1); pk[1] = pkbf(p2, p3);
        *(uint2v*)(&Ps[qrow * FLD + ni * 16 + quad * 4]) = pk;
      }
      // O^T += V^T·P (wave-local, no barrier)
      short8 bp[2];
      #pragma unroll
      for (int ks = 0; ks < 2; ks++)
        bp[ks] = *(const short8*)(&Ps[qrow * FLD + ks * 32 + quad * 8]);
      __builtin_amdgcn_s_setprio(1);
      #pragma unroll
      for (int mi = 0; mi < 4; mi++) {
        #pragma unroll
        for (int ks = 0; ks < 2; ks++) {
          short8 av = *(const short8*)(&Vs[buf][(mi * 16 + l15) * 64 +
                                               (((ks * 4 + quad) ^ sw) * 8)]);
          oacc[g][mi] = __builtin_amdgcn_mfma_f32_16x16x32_bf16(av, bp[ks], oacc[g][mi], 0, 0, 0);
        }
      }
      __builtin_amdgcn_s_setprio(0);
    }
    // ---- pipeline: all waves done reading buf -> refill it with kt+2
    __builtin_amdgcn_s_barrier();
    if (kt + 2 < 16) { STAGE_KV(kt + 2, Ks[buf], Vs[buf]); }
    if (kt + 1 < 16) {
      if (kt + 2 < 16) asm volatile("s_waitcnt vmcnt(2)" ::: "memory");
      else             asm volatile("s_waitcnt vmcnt(0)" ::: "memory");
      __builtin_amdgcn_s_barrier();   // tile kt+1 landed for all waves
    }
  }
  #undef STAGE_KV

  #pragma unroll
  for (int g = 0; g < 4; g++) {
    float l_tot = psum[g];
    l_tot += __shfl_xor(l_tot, 16, 64);
    l_tot += __shfl_xor(l_tot, 32, 64);
    const float linv = 1.0f / l_tot;
    const int t = q0 + wv * 64 + g * 16 + l15;
    #pragma unroll
    for (int mi = 0; mi < 4; mi++) {
      uint2v yk;
      yk[0] = pkbf(oacc[g][mi][0] * linv, oacc[g][mi][1] * linv);
      yk[1] = pkbf(oacc[g][mi][2] * linv, oacc[g][mi][3] * linv);
      *(uint2v*)(Y + (size_t)(b * 1024 + t) * 1024 + h * 64 + mi * 16 + quad * 4) = yk;
    }
  }
}

// ---------------------------------------------------------------- launch
extern "C" void kernel_launch(void* const* d_in, const int* in_sizes, int n_in,
                              void* d_out, int out_size, void* d_ws, size_t ws_size,
                              hipStream_t stream) {
  const float* x      = (const float*)d_in[0];  // [8,1024,1024] fp32
  const float* W_attn = (const float*)d_in[1];  // [1024,3072]   fp32
  const float* W_proj = (const float*)d_in[2];  // [1024,1024]   fp32
  const float* omega  = (const float*)d_in[3];  // [32]          fp32
  float* out = (float*)d_out;                   // [8192,1024]   fp32

  uint16_t* wsp     = (uint16_t*)d_ws;
  uint16_t* xb      = wsp;                                  // 8,388,608
  uint16_t* Wt_attn = xb + (size_t)8192 * 1024;             // 3,145,728
  uint16_t* Wt_proj = Wt_attn + (size_t)3072 * 1024;        // 1,048,576
  uint16_t* Qr      = Wt_proj + (size_t)1024 * 1024;        // 8,388,608
  uint16_t* Kr      = Qr + (size_t)128 * 1024 * 64;         // 8,388,608
  uint16_t* Vt      = Kr + (size_t)128 * 1024 * 64;         // 8,388,608
  float2*   ropet   = (float2*)(Vt + (size_t)128 * 1024 * 64);  // 32768 float2
  uint16_t* Y       = xb;   // xb dead after gemm_qkv

  prep<<<5248, 256, 0, stream>>>(x, W_attn, W_proj, omega, xb, Wt_attn, Wt_proj, ropet);
  gemm_qkv<<<768, 512, 0, stream>>>(xb, Wt_attn, ropet, Qr, Kr, Vt);
  flash_attn<<<256, 512, 0, stream>>>(Qr, Kr, Vt, Y);
  gemm_out<<<256, 512, 0, stream>>>(Y, Wt_proj, out, 8192, 1024, 1024);
}